// Round 5
// baseline (830.621 us; speedup 1.0000x reference)
//
#include <hip/hip_runtime.h>
#include <hip/hip_bf16.h>
#include <math.h>

using short8 = __attribute__((ext_vector_type(8))) short;
using f32x16 = __attribute__((ext_vector_type(16))) float;

constexpr int B  = 1024;
constexpr int NN = 128;   // nodes per tree
constexpr int F  = 318;   // raw features

__device__ inline float bf2f(unsigned short u) {
    union { unsigned int i; float f; } x; x.i = ((unsigned int)u) << 16; return x.f;
}
__device__ inline unsigned short f2bf(float f) {
    union { float f; unsigned int i; } x; x.f = f;
    unsigned int r = x.i + 0x7fff + ((x.i >> 16) & 1);
    return (unsigned short)(r >> 16);
}

// ---------- weight prepack into 32x32x16 MFMA B-fragment order ----------
// element t = ((kbg*(COUT/32)+ob)*64+lane)*8+j
// kbg = (k*NCC + cc)*KS + ks ; c = cc*CC + ks*16 + (lane>>5)*8 + j ; o = ob*32 + (lane&31)
__global__ __launch_bounds__(256) void prepack_w32(const float* __restrict__ w,
                                                   unsigned short* __restrict__ wp,
                                                   int kmul, int OREAL, int CREAL,
                                                   int CC, int COUT, int KS, int NCC, int KTOT)
{
    int t = blockIdx.x * 256 + threadIdx.x;
    if (t >= KTOT * COUT) return;
    int j = t & 7;
    int lane = (t >> 3) & 63;
    int rest = t >> 9;
    int obn = COUT / 32;
    int ob = rest % obn;
    int kbg = rest / obn;
    int ks = kbg % KS;
    int t2 = kbg / KS;
    int cc = t2 % NCC;
    int k  = t2 / NCC;
    int c = cc * CC + ks * 16 + (lane >> 5) * 8 + j;
    int o = ob * 32 + (lane & 31);
    float v = 0.f;
    if (c < CREAL && o < OREAL)
        v = (kmul == 3) ? w[((size_t)o * CREAL + c) * 3 + k] : w[(size_t)o * CREAL + c];
    wp[t] = f2bf(v);
}

// ---------- encoder, fused transpose: trees [B][F][NN] f32 -> x0 [B][NN][128] bf16 ----------
// x0[b,n,o] = bias[o] + sum_c enc_w[o,c] * trees[b,c,n]
__global__ __launch_bounds__(256, 2) void enc_fused(const float* __restrict__ trees,
                                                    const unsigned short* __restrict__ wp,
                                                    const float* __restrict__ bias,
                                                    unsigned short* __restrict__ x0)
{
    constexpr int CC = 64, NCH = 5, KS = 4, NB = 4, OT = 128;
    constexpr int BUFB = NN * CC * 2;       // 16 KB
    __shared__ __align__(16) char gbuf[2 * BUFB];   // dbuf; epilogue reuses 32 KB

    const int b = blockIdx.x;
    const int tid = threadIdx.x;
    const int lane = tid & 63;
    const int wm = tid >> 6;                 // wave = 32 rows
    const int l31 = lane & 31, lh2 = lane >> 5;

    const int cl = tid >> 2;                 // channel-within-chunk 0..63
    const int nq = tid & 3;                  // n-quarter

    float4 vv[8];
    auto load = [&](int ch) {
        const int c = ch * CC + cl;
        const bool ok = (c < F);
        const float* src = trees + ((size_t)b * F + c) * NN + nq * 32;
#pragma unroll
        for (int j = 0; j < 8; ++j)
            vv[j] = ok ? *reinterpret_cast<const float4*>(src + j * 4) : make_float4(0.f, 0.f, 0.f, 0.f);
    };
    const int gsw = cl >> 3, cby = (cl & 7) * 2;
    auto stor = [&](char* wb) {
#pragma unroll
        for (int j = 0; j < 8; ++j) {
            const int n0 = nq * 32 + j * 4;
            const float f4[4] = {vv[j].x, vv[j].y, vv[j].z, vv[j].w};
#pragma unroll
            for (int r = 0; r < 4; ++r) {
                const int n = n0 + r;
                *reinterpret_cast<unsigned short*>(
                    wb + n * (CC * 2) + (((gsw ^ (n & 7)) << 4) + cby)) = f2bf(f4[r]);
            }
        }
    };

    f32x16 acc[NB];
#pragma unroll
    for (int ob = 0; ob < NB; ++ob) acc[ob] = (f32x16)0.f;

    const int nrow = wm * 32 + l31;
    const unsigned abyte = (unsigned)(nrow * (CC * 2));
    const unsigned axor = (unsigned)((nrow & 7) << 4);

    load(0); stor(gbuf);
    __syncthreads();

    int p = 0;
#pragma unroll
    for (int ch = 0; ch < NCH; ++ch) {
        if (ch + 1 < NCH) load(ch + 1);
        const char* base = gbuf + p * BUFB;
#pragma unroll
        for (int ks = 0; ks < KS; ++ks) {
            const int kbg = ch * KS + ks;
            short8 a = *reinterpret_cast<const short8*>(
                base + abyte + (((unsigned)((ks * 2 + lh2) << 4)) ^ axor));
            const unsigned short* wb_ = wp + ((size_t)(kbg * 4) * 64 + lane) * 8;
#pragma unroll
            for (int ob = 0; ob < NB; ++ob) {
                short8 bf_ = *reinterpret_cast<const short8*>(wb_ + ob * 512);
                acc[ob] = __builtin_amdgcn_mfma_f32_32x32x16_bf16(a, bf_, acc[ob], 0, 0, 0);
            }
        }
        if (ch + 1 < NCH) stor(gbuf + (p ^ 1) * BUFB);
        __syncthreads();
        p ^= 1;
    }

    // epilogue
    unsigned short* xs = reinterpret_cast<unsigned short*>(gbuf);
    float bs[NB];
#pragma unroll
    for (int ob = 0; ob < NB; ++ob) {
        int o = ob * 32 + l31;
        bs[ob] = (o < 109) ? bias[o] : 0.f;
    }
#pragma unroll
    for (int ob = 0; ob < NB; ++ob)
#pragma unroll
        for (int r = 0; r < 16; ++r) {
            float val = acc[ob][r] + bs[ob];
            int row = wm * 32 + (r & 3) + 8 * (r >> 2) + 4 * lh2;
            xs[row * OT + ob * 32 + l31] = f2bf(val);
        }
    __syncthreads();
#pragma unroll
    for (int i = 0; i < 8; ++i) {
        int e = i * 256 + tid;
        int n = e >> 4, g = e & 15;
        *reinterpret_cast<uint4*>(x0 + ((size_t)b * NN + n) * 128 + g * 8)
            = *reinterpret_cast<const uint4*>(xs + n * OT + g * 8);
    }
}

// ---------- tree conv as GEMM: dense-stage once, gather at A-frag read ----------
// out[b][n][o] = bias[o] + sum_{k,c} W[o][c][k] * T(x[b][ idx[b][3n+k] ][c])
// T(v) = NORM ? max(v*inv - mu*inv, 0) : v   (applied once at stage time)
template <int CIN, int CC, int NPL, int NB, int COUT, bool NORM, bool STATS>
__global__ __launch_bounds__(256, 2) void conv_gemm(const unsigned short* __restrict__ xin, // [B][NN][CIN]
                                                    const int* __restrict__ idx,            // [B][3*NN]
                                                    const unsigned short* __restrict__ wp,
                                                    const float* __restrict__ bias,
                                                    const float* __restrict__ stats,
                                                    unsigned short* __restrict__ yout,      // [B][NN][COUT]
                                                    float* __restrict__ partials)
{
    constexpr int NCC   = CIN / CC;
    constexpr int KS    = CC / 16;
    constexpr int GR    = CC / 8;             // 16
    constexpr int ITERS = (NN * GR) / 256;    // 8
    constexpr int BUFB  = NN * CC * 2;        // 32 KB
    constexpr int OT    = NB * 32;
    constexpr int EPB   = NN * OT * 2;
    constexpr int DB    = (NCC > 1) ? 2 * BUFB : BUFB;
    constexpr int SMEM  = (DB > EPB) ? DB : EPB;

    __shared__ __align__(16) char gbuf[SMEM];
    __shared__ float rbuf[8];

    const int b = blockIdx.x;
    const int tid = threadIdx.x;
    const int lane = tid & 63;
    const int wm = tid >> 6;
    const int l31 = lane & 31, lh2 = lane >> 5;
    const int ob0 = blockIdx.y * NB;

    float inv = 1.f, nmi = 0.f;
    if (NORM) { float mu = stats[0]; inv = stats[1]; nmi = -mu * inv; }

    const unsigned short* xb = xin + (size_t)b * NN * CIN;

    // dense staging descriptors
    const int g = tid & (GR - 1);
    unsigned ngoff[ITERS], lby[ITERS];
#pragma unroll
    for (int i = 0; i < ITERS; ++i) {
        int n = (i * 256 + tid) >> 4;
        ngoff[i] = (unsigned)(n * CIN + g * 8);
        lby[i]   = (unsigned)(n * (CC * 2) + ((g ^ (n & 7)) << 4));
    }

    // per-lane gathered source rows for the MFMA A-reads
    const int nrow = wm * 32 + l31;
    unsigned sbase[NPL], sx[NPL];
#pragma unroll
    for (int k = 0; k < NPL; ++k) {
        int s = idx[b * 3 * NN + 3 * nrow + k];
        sbase[k] = (unsigned)(s * (CC * 2));
        sx[k] = (unsigned)((s & 7) << 4);
    }

    f32x16 acc[NB];
#pragma unroll
    for (int ob = 0; ob < NB; ++ob) acc[ob] = (f32x16)0.f;

    uint4 v[ITERS];
    auto load = [&](int cc) {
#pragma unroll
        for (int i = 0; i < ITERS; ++i)
            v[i] = *reinterpret_cast<const uint4*>(xb + cc * CC + ngoff[i]);
    };
    auto stor = [&](char* wb) {
#pragma unroll
        for (int i = 0; i < ITERS; ++i) {
            uint4 t = v[i];
            if (NORM) {
                unsigned int* pw = reinterpret_cast<unsigned int*>(&t);
#pragma unroll
                for (int q = 0; q < 4; ++q) {
                    unsigned int u = pw[q];
                    float f0 = __uint_as_float(u << 16);
                    float f1 = __uint_as_float(u & 0xffff0000u);
                    f0 = fmaxf(fmaf(f0, inv, nmi), 0.f);
                    f1 = fmaxf(fmaf(f1, inv, nmi), 0.f);
                    unsigned int r;
                    asm("v_cvt_pk_bf16_f32 %0, %1, %2" : "=v"(r) : "v"(f0), "v"(f1));
                    pw[q] = r;
                }
            }
            *reinterpret_cast<uint4*>(wb + lby[i]) = t;
        }
    };

    load(0); stor(gbuf);
    __syncthreads();

    int p = 0;
#pragma unroll
    for (int cc = 0; cc < NCC; ++cc) {
        if (cc + 1 < NCC) load(cc + 1);
        const char* base = gbuf + p * BUFB;
#pragma unroll
        for (int k = 0; k < NPL; ++k) {
            const unsigned ab = sbase[k], ax = sx[k];
#pragma unroll
            for (int ks = 0; ks < KS; ++ks) {
                const int kbg = (k * NCC + cc) * KS + ks;
                short8 a = *reinterpret_cast<const short8*>(
                    base + ab + (((unsigned)((ks * 2 + lh2) << 4)) ^ ax));
                const unsigned short* wb_ = wp + (((size_t)kbg * (COUT / 32) + ob0) * 64 + lane) * 8;
#pragma unroll
                for (int ob = 0; ob < NB; ++ob) {
                    short8 bf_ = *reinterpret_cast<const short8*>(wb_ + ob * 512);
                    acc[ob] = __builtin_amdgcn_mfma_f32_32x32x16_bf16(a, bf_, acc[ob], 0, 0, 0);
                }
            }
        }
        if (cc + 1 < NCC) stor(gbuf + (p ^ 1) * BUFB);
        __syncthreads();
        p ^= 1;
    }

    // ---------------- epilogue: bias, stats, coalesced store via LDS tile ----------------
    unsigned short* xs = reinterpret_cast<unsigned short*>(gbuf);
    float bs[NB];
#pragma unroll
    for (int ob = 0; ob < NB; ++ob) bs[ob] = bias[blockIdx.y * OT + ob * 32 + l31];
    float tsum = 0.f, tss = 0.f;
#pragma unroll
    for (int ob = 0; ob < NB; ++ob)
#pragma unroll
        for (int r = 0; r < 16; ++r) {
            float val = acc[ob][r] + bs[ob];
            if (STATS) { tsum += val; tss += val * val; }
            int row = wm * 32 + (r & 3) + 8 * (r >> 2) + 4 * lh2;
            xs[row * OT + ob * 32 + l31] = f2bf(val);
        }
    __syncthreads();
    constexpr int GRO = OT / 8;
#pragma unroll
    for (int i = 0; i < (NN * GRO) / 256; ++i) {
        int e = i * 256 + tid;
        int n = e / GRO, gg = e % GRO;
        *reinterpret_cast<uint4*>(yout + ((size_t)b * NN + n) * COUT + blockIdx.y * OT + gg * 8)
            = *reinterpret_cast<const uint4*>(xs + n * OT + gg * 8);
    }

    if (STATS) {
#pragma unroll
        for (int s = 32; s; s >>= 1) { tsum += __shfl_down(tsum, s); tss += __shfl_down(tss, s); }
        if (lane == 0) { rbuf[wm * 2] = tsum; rbuf[wm * 2 + 1] = tss; }
        __syncthreads();
        if (tid == 0) {
            float s = rbuf[0] + rbuf[2] + rbuf[4] + rbuf[6];
            float q = rbuf[1] + rbuf[3] + rbuf[5] + rbuf[7];
            int gid = blockIdx.y * gridDim.x + blockIdx.x;
            partials[2 * gid] = s;
            partials[2 * gid + 1] = q;
        }
    }
}

// ---------- finalize global layernorm stats ----------
__global__ __launch_bounds__(256) void stats_kernel(const float* __restrict__ partials,
                                                    float* __restrict__ stats,
                                                    int npart, double ntot)
{
    __shared__ double sd[256], sd2[256];
    double s = 0.0, s2 = 0.0;
    for (int i = threadIdx.x; i < npart; i += 256) { s += (double)partials[2 * i]; s2 += (double)partials[2 * i + 1]; }
    sd[threadIdx.x] = s; sd2[threadIdx.x] = s2;
    __syncthreads();
    for (int k = 128; k > 0; k >>= 1) {
        if (threadIdx.x < k) { sd[threadIdx.x] += sd[threadIdx.x + k]; sd2[threadIdx.x] += sd2[threadIdx.x + k]; }
        __syncthreads();
    }
    if (threadIdx.x == 0) {
        double mu = sd[0] / ntot;
        double var = (sd2[0] - sd[0] * sd[0] / ntot) / (ntot - 1.0);
        double sdv = sqrt(var > 0.0 ? var : 0.0);
        stats[0] = (float)mu;
        stats[1] = (float)(1.0 / (sdv + 1e-5));
    }
}

// ---------- pooling + both heads (coalesced loads + LDS reduce) ----------
__global__ __launch_bounds__(256) void pool_head_kernel(const unsigned short* __restrict__ y3, // [B][NN][128]
                                                        const float* __restrict__ stats,
                                                        const float* __restrict__ latw,
                                                        const float* __restrict__ latb,
                                                        const float* __restrict__ costw,
                                                        const float* __restrict__ costb,
                                                        float* __restrict__ out)
{
    __shared__ float pmax[16][128];
    __shared__ float pl[128];
    const int b = blockIdx.x, t = threadIdx.x;
    const float mu = stats[0], inv = stats[1];
    const int g = t & 15;
    float pm[8];
#pragma unroll
    for (int j = 0; j < 8; ++j) pm[j] = -1e30f;
#pragma unroll
    for (int i = 0; i < 8; ++i) {
        const int n = (t >> 4) + i * 16;
        uint4 vq = *reinterpret_cast<const uint4*>(y3 + ((size_t)b * NN + n) * 128 + g * 8);
        const unsigned int* pw = reinterpret_cast<const unsigned int*>(&vq);
#pragma unroll
        for (int q = 0; q < 4; ++q) {
            pm[2 * q]     = fmaxf(pm[2 * q],     bf2f((unsigned short)(pw[q] & 0xffff)));
            pm[2 * q + 1] = fmaxf(pm[2 * q + 1], bf2f((unsigned short)(pw[q] >> 16)));
        }
    }
#pragma unroll
    for (int j = 0; j < 8; ++j) pmax[t >> 4][g * 8 + j] = pm[j];
    __syncthreads();
    if (t < 128) {
        float m = pmax[0][t];
#pragma unroll
        for (int r = 1; r < 16; ++r) m = fmaxf(m, pmax[r][t]);
        pl[t] = fmaxf((m - mu) * inv, 0.f);
    }
    __syncthreads();
    if (t < 128) {
        const float* w = (t < 64) ? latw : costw;
        const int l = t & 63;
        float v = pl[l] * w[l] + pl[l + 64] * w[l + 64];
#pragma unroll
        for (int s = 32; s > 0; s >>= 1) v += __shfl_down(v, s);
        if (l == 0) {
            const float bb = (t < 64) ? latb[0] : costb[0];
            out[(t < 64 ? 0 : B) + b] = 1.f / (1.f + expf(-(v + bb)));
        }
    }
}

// ---------- launch ----------
extern "C" void kernel_launch(void* const* d_in, const int* in_sizes, int n_in,
                              void* d_out, int out_size, void* d_ws, size_t ws_size,
                              hipStream_t stream)
{
    (void)in_sizes; (void)n_in; (void)out_size; (void)ws_size;
    const float* trees   = (const float*)d_in[0];
    const int*   indexes = (const int*)  d_in[1];
    const float* enc_w   = (const float*)d_in[2];
    const float* enc_b   = (const float*)d_in[3];
    const float* w1 = (const float*)d_in[4];
    const float* b1 = (const float*)d_in[5];
    const float* w2 = (const float*)d_in[6];
    const float* b2 = (const float*)d_in[7];
    const float* w3 = (const float*)d_in[8];
    const float* b3 = (const float*)d_in[9];
    const float* lat_w  = (const float*)d_in[10];
    const float* lat_b  = (const float*)d_in[11];
    const float* cost_w = (const float*)d_in[12];
    const float* cost_b = (const float*)d_in[13];
    float* out = (float*)d_out;

    char* ws = (char*)d_ws;
    size_t off = 0;
    auto alloc = [&](size_t bytes) -> char* {
        char* p = ws + off;
        off += (bytes + 255) & ~(size_t)255;
        return p;
    };
    unsigned short* wpe = (unsigned short*)alloc((size_t)320 * 128 * 2);
    unsigned short* wp1 = (unsigned short*)alloc((size_t)384 * 512 * 2);
    unsigned short* wp2 = (unsigned short*)alloc((size_t)1536 * 256 * 2);
    unsigned short* wp3 = (unsigned short*)alloc((size_t)768 * 128 * 2);
    unsigned short* x0  = (unsigned short*)alloc((size_t)B * NN * 128 * 2);
    unsigned short* y1  = (unsigned short*)alloc((size_t)B * NN * 512 * 2);
    unsigned short* y2  = (unsigned short*)alloc((size_t)B * NN * 256 * 2);
    unsigned short* y3  = (unsigned short*)alloc((size_t)B * NN * 128 * 2);
    float* partials = (float*)alloc((size_t)4096 * 2 * 4);
    float* stats    = (float*)alloc(8 * 4);

    prepack_w32<<<dim3((320 * 128 + 255) / 256),  dim3(256), 0, stream>>>(enc_w, wpe, 1, 109, 318, 64, 128, 4, 5, 320);
    prepack_w32<<<dim3((384 * 512 + 255) / 256),  dim3(256), 0, stream>>>(w1, wp1, 3, 512, 109, 128, 512, 8, 1, 384);
    prepack_w32<<<dim3((1536 * 256 + 255) / 256), dim3(256), 0, stream>>>(w2, wp2, 3, 256, 512, 128, 256, 8, 4, 1536);
    prepack_w32<<<dim3((768 * 128 + 255) / 256),  dim3(256), 0, stream>>>(w3, wp3, 3, 128, 256, 128, 128, 8, 2, 768);

    // encoder (fused transpose): trees -> x0 [B][NN][128]
    enc_fused<<<dim3(B), dim3(256), 0, stream>>>(trees, wpe, enc_b, x0);

    // conv1: [B][NN][384K] @ [384][512] -> y1 (2 o-tiles of 256)
    conv_gemm<128, 128, 3, 8, 512, false, true>
        <<<dim3(B, 2), dim3(256), 0, stream>>>(x0, indexes, wp1, b1, stats, y1, partials);
    stats_kernel<<<dim3(1), dim3(256), 0, stream>>>(partials, stats + 0, 2048, (double)((size_t)B * 512 * NN));

    // conv2: [B][NN][1536K] @ [1536][256] -> y2 (full 256-o per block)
    conv_gemm<512, 128, 3, 8, 256, true, true>
        <<<dim3(B, 1), dim3(256), 0, stream>>>(y1, indexes, wp2, b2, stats + 0, y2, partials);
    stats_kernel<<<dim3(1), dim3(256), 0, stream>>>(partials, stats + 2, 1024, (double)((size_t)B * 256 * NN));

    // conv3: [B][NN][768K] @ [768][128] -> y3
    conv_gemm<256, 128, 3, 4, 128, true, true>
        <<<dim3(B, 1), dim3(256), 0, stream>>>(y2, indexes, wp3, b3, stats + 2, y3, partials);
    stats_kernel<<<dim3(1), dim3(256), 0, stream>>>(partials, stats + 4, 1024, (double)((size_t)B * 128 * NN));

    pool_head_kernel<<<dim3(B), dim3(256), 0, stream>>>(y3, stats + 4, lat_w, lat_b, cost_w, cost_b, out);
}

// Round 6
// 472.853 us; speedup vs baseline: 1.7566x; 1.7566x over previous
//
#include <hip/hip_runtime.h>
#include <hip/hip_bf16.h>
#include <math.h>

using short8 = __attribute__((ext_vector_type(8))) short;
using f32x16 = __attribute__((ext_vector_type(16))) float;

constexpr int B  = 1024;
constexpr int NN = 128;   // nodes per tree
constexpr int F  = 318;   // raw features

__device__ inline float bf2f(unsigned short u) {
    union { unsigned int i; float f; } x; x.i = ((unsigned int)u) << 16; return x.f;
}
__device__ inline unsigned short f2bf(float f) {
    union { float f; unsigned int i; } x; x.f = f;
    unsigned int r = x.i + 0x7fff + ((x.i >> 16) & 1);
    return (unsigned short)(r >> 16);
}

// ---------- weight prepack into 32x32x16 MFMA B-fragment order ----------
// element t = ((kbg*(COUT/32)+ob)*64+lane)*8+j
// kbg = (k*NCC + cc)*KS + ks ; c = cc*CC + ks*16 + (lane>>5)*8 + j ; o = ob*32 + (lane&31)
__global__ __launch_bounds__(256) void prepack_w32(const float* __restrict__ w,
                                                   unsigned short* __restrict__ wp,
                                                   int kmul, int OREAL, int CREAL,
                                                   int CC, int COUT, int KS, int NCC, int KTOT)
{
    int t = blockIdx.x * 256 + threadIdx.x;
    if (t >= KTOT * COUT) return;
    int j = t & 7;
    int lane = (t >> 3) & 63;
    int rest = t >> 9;
    int obn = COUT / 32;
    int ob = rest % obn;
    int kbg = rest / obn;
    int ks = kbg % KS;
    int t2 = kbg / KS;
    int cc = t2 % NCC;
    int k  = t2 / NCC;
    int c = cc * CC + ks * 16 + (lane >> 5) * 8 + j;
    int o = ob * 32 + (lane & 31);
    float v = 0.f;
    if (c < CREAL && o < OREAL)
        v = (kmul == 3) ? w[((size_t)o * CREAL + c) * 3 + k] : w[(size_t)o * CREAL + c];
    wp[t] = f2bf(v);
}

// ---------- encoder, fused transpose: trees [B][F][NN] f32 -> x0 [B][NN][128] bf16 ----------
__global__ __launch_bounds__(256, 2) void enc_fused(const float* __restrict__ trees,
                                                    const unsigned short* __restrict__ wp,
                                                    const float* __restrict__ bias,
                                                    unsigned short* __restrict__ x0)
{
    constexpr int CC = 64, NCH = 5, KS = 4, NB = 4, OT = 128;
    constexpr int BUFB = NN * CC * 2;       // 16 KB
    __shared__ __align__(16) char gbuf[2 * BUFB];   // dbuf; epilogue reuses 32 KB

    const int b = blockIdx.x;
    const int tid = threadIdx.x;
    const int lane = tid & 63;
    const int wm = tid >> 6;                 // wave = 32 rows
    const int l31 = lane & 31, lh2 = lane >> 5;

    const int cl = tid >> 2;                 // channel-within-chunk 0..63
    const int nq = tid & 3;                  // n-quarter

    float4 vv[8];
    auto load = [&](int ch) {
        const int c = ch * CC + cl;
        const bool ok = (c < F);
        const float* src = trees + ((size_t)b * F + c) * NN + nq * 32;
#pragma unroll
        for (int j = 0; j < 8; ++j)
            vv[j] = ok ? *reinterpret_cast<const float4*>(src + j * 4) : make_float4(0.f, 0.f, 0.f, 0.f);
    };
    const int gsw = cl >> 3, cby = (cl & 7) * 2;
    auto stor = [&](char* wb) {
#pragma unroll
        for (int j = 0; j < 8; ++j) {
            const int n0 = nq * 32 + j * 4;
            const float f4[4] = {vv[j].x, vv[j].y, vv[j].z, vv[j].w};
#pragma unroll
            for (int r = 0; r < 4; ++r) {
                const int n = n0 + r;
                *reinterpret_cast<unsigned short*>(
                    wb + n * (CC * 2) + (((gsw ^ (n & 7)) << 4) + cby)) = f2bf(f4[r]);
            }
        }
    };

    f32x16 acc[NB];
#pragma unroll
    for (int ob = 0; ob < NB; ++ob) acc[ob] = (f32x16)0.f;

    const int nrow = wm * 32 + l31;
    const unsigned abyte = (unsigned)(nrow * (CC * 2));
    const unsigned axor = (unsigned)((nrow & 7) << 4);

    load(0); stor(gbuf);
    __syncthreads();

    int p = 0;
#pragma unroll
    for (int ch = 0; ch < NCH; ++ch) {
        if (ch + 1 < NCH) load(ch + 1);
        const char* base = gbuf + p * BUFB;
#pragma unroll
        for (int ks = 0; ks < KS; ++ks) {
            const int kbg = ch * KS + ks;
            short8 a = *reinterpret_cast<const short8*>(
                base + abyte + (((unsigned)((ks * 2 + lh2) << 4)) ^ axor));
            const unsigned short* wb_ = wp + ((size_t)(kbg * 4) * 64 + lane) * 8;
#pragma unroll
            for (int ob = 0; ob < NB; ++ob) {
                short8 bf_ = *reinterpret_cast<const short8*>(wb_ + ob * 512);
                acc[ob] = __builtin_amdgcn_mfma_f32_32x32x16_bf16(a, bf_, acc[ob], 0, 0, 0);
            }
        }
        if (ch + 1 < NCH) stor(gbuf + (p ^ 1) * BUFB);
        __syncthreads();
        p ^= 1;
    }

    // epilogue
    unsigned short* xs = reinterpret_cast<unsigned short*>(gbuf);
    float bs[NB];
#pragma unroll
    for (int ob = 0; ob < NB; ++ob) {
        int o = ob * 32 + l31;
        bs[ob] = (o < 109) ? bias[o] : 0.f;
    }
#pragma unroll
    for (int ob = 0; ob < NB; ++ob)
#pragma unroll
        for (int r = 0; r < 16; ++r) {
            float val = acc[ob][r] + bs[ob];
            int row = wm * 32 + (r & 3) + 8 * (r >> 2) + 4 * lh2;
            xs[row * OT + ob * 32 + l31] = f2bf(val);
        }
    __syncthreads();
#pragma unroll
    for (int i = 0; i < 8; ++i) {
        int e = i * 256 + tid;
        int n = e >> 4, g = e & 15;
        *reinterpret_cast<uint4*>(x0 + ((size_t)b * NN + n) * 128 + g * 8)
            = *reinterpret_cast<const uint4*>(xs + n * OT + g * 8);
    }
}

// ---------- tree conv: DENSE GEMM (3 weight planes share staged A) + output-side gather ----------
// Z_k = T(x) @ W_k^T computed dense; y[n][o] = bias[o] + sum_k Z_k[idx[3n+k]][o]
// T(v) = NORM ? max(v*inv - mu*inv, 0) : v  (once, at stage time)
// COLMAX: emit per-column max over n (raw, biased) instead of y (for final layer + pooling).
template <int CIN, int COUT, bool NORM, bool COLMAX>
__global__ __launch_bounds__(256, 2) void conv_gemm(const unsigned short* __restrict__ xin, // [B][NN][CIN]
                                                    const int* __restrict__ idx,            // [B][3*NN]
                                                    const unsigned short* __restrict__ wp,
                                                    const float* __restrict__ bias,
                                                    const float* __restrict__ stats,
                                                    unsigned short* __restrict__ yout,      // [B][NN][COUT]
                                                    float* __restrict__ colmax,             // [B][COUT]
                                                    float* __restrict__ partials)
{
    constexpr int CC    = 128;
    constexpr int NCC   = CIN / CC;
    constexpr int KS    = 8;                  // k-steps per chunk (CC/16)
    constexpr int ITERS = 8;                  // staging granules per thread
    constexpr int BUFB  = NN * CC * 2;        // 32 KB
    constexpr int DB    = (NCC > 1) ? 2 * BUFB : BUFB;
    constexpr int ZB    = 3 * NN * 32 * 4;    // 48 KB f32 Z tiles
    constexpr int SMEM  = (DB > ZB) ? DB : ZB;

    __shared__ __align__(16) char gbuf[SMEM];
    __shared__ float rbuf[8];
    __shared__ float cmax[4][2][16];

    const int b  = blockIdx.x;
    const int oy = blockIdx.y;                // o-tile base = oy*64
    const int tid = threadIdx.x;
    const int lane = tid & 63;
    const int wv = tid >> 6;
    const int wm = wv >> 1, wn = wv & 1;
    const int l31 = lane & 31, lh2 = lane >> 5;

    float inv = 1.f, nmi = 0.f;
    if (NORM) { float mu = stats[0]; inv = stats[1]; nmi = -mu * inv; }

    const unsigned short* xb = xin + (size_t)b * NN * CIN;

    // dense staging descriptors (coalesced global, swizzled LDS)
    const int g = tid & 15;
    unsigned ngoff[ITERS], lby[ITERS];
#pragma unroll
    for (int i = 0; i < ITERS; ++i) {
        int n = (i * 256 + tid) >> 4;
        ngoff[i] = (unsigned)(n * CIN + g * 8);
        lby[i]   = (unsigned)(n * 256 + ((g ^ (n & 15)) << 4));
    }

    // gather rows for the epilogue (per-thread output row)
    const int en = tid >> 1, eh = tid & 1;
    int sk[3];
#pragma unroll
    for (int k = 0; k < 3; ++k) sk[k] = idx[b * 3 * NN + 3 * en + k];

    f32x16 acc[2][3];                          // [nfrag][kplane]
#pragma unroll
    for (int nf = 0; nf < 2; ++nf)
#pragma unroll
        for (int k = 0; k < 3; ++k) acc[nf][k] = (f32x16)0.f;

    uint4 v[ITERS];
    auto load = [&](int cc) {
#pragma unroll
        for (int i = 0; i < ITERS; ++i)
            v[i] = *reinterpret_cast<const uint4*>(xb + cc * CC + ngoff[i]);
    };
    auto stor = [&](char* wb) {
#pragma unroll
        for (int i = 0; i < ITERS; ++i) {
            uint4 t = v[i];
            if (NORM) {
                unsigned int* pw = reinterpret_cast<unsigned int*>(&t);
#pragma unroll
                for (int q = 0; q < 4; ++q) {
                    unsigned int u = pw[q];
                    float f0 = __uint_as_float(u << 16);
                    float f1 = __uint_as_float(u & 0xffff0000u);
                    f0 = fmaxf(fmaf(f0, inv, nmi), 0.f);
                    f1 = fmaxf(fmaf(f1, inv, nmi), 0.f);
                    unsigned int r;
                    asm("v_cvt_pk_bf16_f32 %0, %1, %2" : "=v"(r) : "v"(f0), "v"(f1));
                    pw[q] = r;
                }
            }
            *reinterpret_cast<uint4*>(wb + lby[i]) = t;
        }
    };

    // A-read bases: rows wave-deterministic (dense!)
    const int n0 = wm * 64 + l31;
    const int n1 = n0 + 32;
    const unsigned a0b = (unsigned)(n0 * 256), a0x = (unsigned)((n0 & 15) << 4);
    const unsigned a1b = (unsigned)(n1 * 256), a1x = (unsigned)((n1 & 15) << 4);
    const int obg = oy * 2 + wn;

    load(0); stor(gbuf);
    __syncthreads();

    int p = 0;
#pragma unroll
    for (int cc = 0; cc < NCC; ++cc) {
        if (cc + 1 < NCC) load(cc + 1);
        const char* base = gbuf + p * BUFB;
#pragma unroll
        for (int ks = 0; ks < KS; ++ks) {
            const unsigned so = (unsigned)((ks * 2 + lh2) << 4);
            short8 a0 = *reinterpret_cast<const short8*>(base + a0b + (so ^ a0x));
            short8 a1 = *reinterpret_cast<const short8*>(base + a1b + (so ^ a1x));
#pragma unroll
            for (int k = 0; k < 3; ++k) {
                const size_t kbg = (size_t)((k * NCC + cc) * KS + ks);
                short8 bf_ = *reinterpret_cast<const short8*>(
                    wp + ((kbg * (COUT / 32) + obg) * 64 + lane) * 8);
                acc[0][k] = __builtin_amdgcn_mfma_f32_32x32x16_bf16(a0, bf_, acc[0][k], 0, 0, 0);
                acc[1][k] = __builtin_amdgcn_mfma_f32_32x32x16_bf16(a1, bf_, acc[1][k], 0, 0, 0);
            }
        }
        if (cc + 1 < NCC) stor(gbuf + (p ^ 1) * BUFB);
        __syncthreads();
        p ^= 1;
    }

    // ---------------- epilogue: Z -> LDS (f32, quad-swizzled), output-side gather ----------------
    float* Z = reinterpret_cast<float*>(gbuf);
    float tsum = 0.f, tss = 0.f;
#pragma unroll
    for (int oh = 0; oh < 2; ++oh) {
        if (oh) __syncthreads();
        if (wn == oh) {
#pragma unroll
            for (int k = 0; k < 3; ++k)
#pragma unroll
                for (int nf = 0; nf < 2; ++nf)
#pragma unroll
                    for (int r = 0; r < 16; ++r) {
                        int row = wm * 64 + nf * 32 + (r & 3) + 8 * (r >> 2) + 4 * lh2;
                        Z[(k * NN + row) * 32 + (l31 ^ ((row & 7) << 2))] = acc[nf][k][r];
                    }
        }
        __syncthreads();

        // per-thread: 16 outputs, row en, cols eh*16..+15 of this o-half
        float val[16];
        {
            const float* bp = bias + oy * 64 + oh * 32 + eh * 16;
#pragma unroll
            for (int j = 0; j < 16; ++j) val[j] = bp[j];
        }
#pragma unroll
        for (int k = 0; k < 3; ++k) {
            const float* zr = Z + (k * NN + sk[k]) * 32;
            const int sw = sk[k] & 7;
#pragma unroll
            for (int q4 = 0; q4 < 4; ++q4) {
                const int q = eh * 4 + q4;
                float4 z = *reinterpret_cast<const float4*>(zr + ((q ^ sw) << 2));
                val[q4 * 4 + 0] += z.x;
                val[q4 * 4 + 1] += z.y;
                val[q4 * 4 + 2] += z.z;
                val[q4 * 4 + 3] += z.w;
            }
        }
#pragma unroll
        for (int j = 0; j < 16; ++j) { tsum += val[j]; tss += val[j] * val[j]; }

        if (COLMAX) {
            // butterfly max across the 32 n-rows in this wave (keep col-half parity = lane bit0)
#pragma unroll
            for (int m = 2; m <= 32; m <<= 1)
#pragma unroll
                for (int j = 0; j < 16; ++j) val[j] = fmaxf(val[j], __shfl_xor(val[j], m));
            if ((lane >> 1) == 0) {
#pragma unroll
                for (int j = 0; j < 16; ++j) cmax[wv][lane & 1][j] = val[j];
            }
            __syncthreads();
            if (tid < 32) {
                float m = fmaxf(fmaxf(cmax[0][tid >> 4][tid & 15], cmax[1][tid >> 4][tid & 15]),
                                fmaxf(cmax[2][tid >> 4][tid & 15], cmax[3][tid >> 4][tid & 15]));
                colmax[b * COUT + oy * 64 + oh * 32 + tid] = m;
            }
        } else {
            unsigned int pk[8];
#pragma unroll
            for (int j = 0; j < 8; ++j)
                pk[j] = (unsigned int)f2bf(val[2 * j]) | ((unsigned int)f2bf(val[2 * j + 1]) << 16);
            unsigned short* dst = yout + ((size_t)b * NN + en) * COUT + oy * 64 + oh * 32 + eh * 16;
            reinterpret_cast<uint4*>(dst)[0] = make_uint4(pk[0], pk[1], pk[2], pk[3]);
            reinterpret_cast<uint4*>(dst)[1] = make_uint4(pk[4], pk[5], pk[6], pk[7]);
        }
    }

    // block stats reduction
#pragma unroll
    for (int s = 32; s; s >>= 1) { tsum += __shfl_down(tsum, s); tss += __shfl_down(tss, s); }
    if (lane == 0) { rbuf[wv * 2] = tsum; rbuf[wv * 2 + 1] = tss; }
    __syncthreads();
    if (tid == 0) {
        float s = rbuf[0] + rbuf[2] + rbuf[4] + rbuf[6];
        float q = rbuf[1] + rbuf[3] + rbuf[5] + rbuf[7];
        int gid = blockIdx.y * gridDim.x + blockIdx.x;
        partials[2 * gid] = s;
        partials[2 * gid + 1] = q;
    }
}

// ---------- finalize global layernorm stats ----------
__global__ __launch_bounds__(256) void stats_kernel(const float* __restrict__ partials,
                                                    float* __restrict__ stats,
                                                    int npart, double ntot)
{
    __shared__ double sd[256], sd2[256];
    double s = 0.0, s2 = 0.0;
    for (int i = threadIdx.x; i < npart; i += 256) { s += (double)partials[2 * i]; s2 += (double)partials[2 * i + 1]; }
    sd[threadIdx.x] = s; sd2[threadIdx.x] = s2;
    __syncthreads();
    for (int k = 128; k > 0; k >>= 1) {
        if (threadIdx.x < k) { sd[threadIdx.x] += sd[threadIdx.x + k]; sd2[threadIdx.x] += sd2[threadIdx.x + k]; }
        __syncthreads();
    }
    if (threadIdx.x == 0) {
        double mu = sd[0] / ntot;
        double var = (sd2[0] - sd[0] * sd[0] / ntot) / (ntot - 1.0);
        double sdv = sqrt(var > 0.0 ? var : 0.0);
        stats[0] = (float)mu;
        stats[1] = (float)(1.0 / (sdv + 1e-5));
    }
}

// ---------- heads from per-column max (raw) ----------
__global__ __launch_bounds__(128) void pool_head_kernel(const float* __restrict__ colmax,  // [B][128]
                                                        const float* __restrict__ stats,
                                                        const float* __restrict__ latw,
                                                        const float* __restrict__ latb,
                                                        const float* __restrict__ costw,
                                                        const float* __restrict__ costb,
                                                        float* __restrict__ out)
{
    const int b = blockIdx.x, t = threadIdx.x;
    const float mu = stats[0], inv = stats[1];
    const float pooled = fmaxf((colmax[b * 128 + t] - mu) * inv, 0.f);
    __shared__ float pl[128];
    pl[t] = pooled;
    __syncthreads();
    const float* w = (t < 64) ? latw : costw;
    const int l = t & 63;
    float v = pl[l] * w[l] + pl[l + 64] * w[l + 64];
#pragma unroll
    for (int s = 32; s > 0; s >>= 1) v += __shfl_down(v, s);
    if (l == 0) {
        const float bb = (t < 64) ? latb[0] : costb[0];
        out[(t < 64 ? 0 : B) + b] = 1.f / (1.f + expf(-(v + bb)));
    }
}

// ---------- launch ----------
extern "C" void kernel_launch(void* const* d_in, const int* in_sizes, int n_in,
                              void* d_out, int out_size, void* d_ws, size_t ws_size,
                              hipStream_t stream)
{
    (void)in_sizes; (void)n_in; (void)out_size; (void)ws_size;
    const float* trees   = (const float*)d_in[0];
    const int*   indexes = (const int*)  d_in[1];
    const float* enc_w   = (const float*)d_in[2];
    const float* enc_b   = (const float*)d_in[3];
    const float* w1 = (const float*)d_in[4];
    const float* b1 = (const float*)d_in[5];
    const float* w2 = (const float*)d_in[6];
    const float* b2 = (const float*)d_in[7];
    const float* w3 = (const float*)d_in[8];
    const float* b3 = (const float*)d_in[9];
    const float* lat_w  = (const float*)d_in[10];
    const float* lat_b  = (const float*)d_in[11];
    const float* cost_w = (const float*)d_in[12];
    const float* cost_b = (const float*)d_in[13];
    float* out = (float*)d_out;

    char* ws = (char*)d_ws;
    size_t off = 0;
    auto alloc = [&](size_t bytes) -> char* {
        char* p = ws + off;
        off += (bytes + 255) & ~(size_t)255;
        return p;
    };
    unsigned short* wpe = (unsigned short*)alloc((size_t)320 * 128 * 2);
    unsigned short* wp1 = (unsigned short*)alloc((size_t)384 * 512 * 2);
    unsigned short* wp2 = (unsigned short*)alloc((size_t)1536 * 256 * 2);
    unsigned short* wp3 = (unsigned short*)alloc((size_t)768 * 128 * 2);
    unsigned short* x0  = (unsigned short*)alloc((size_t)B * NN * 128 * 2);
    unsigned short* y1  = (unsigned short*)alloc((size_t)B * NN * 512 * 2);
    unsigned short* y2  = (unsigned short*)alloc((size_t)B * NN * 256 * 2);
    float* colmax   = (float*)alloc((size_t)B * 128 * 4);
    float* partials = (float*)alloc((size_t)8192 * 2 * 4);
    float* stats    = (float*)alloc(8 * 4);

    prepack_w32<<<dim3((320 * 128 + 255) / 256),  dim3(256), 0, stream>>>(enc_w, wpe, 1, 109, 318, 64, 128, 4, 5, 320);
    prepack_w32<<<dim3((384 * 512 + 255) / 256),  dim3(256), 0, stream>>>(w1, wp1, 3, 512, 109, 128, 512, 8, 1, 384);
    prepack_w32<<<dim3((1536 * 256 + 255) / 256), dim3(256), 0, stream>>>(w2, wp2, 3, 256, 512, 128, 256, 8, 4, 1536);
    prepack_w32<<<dim3((768 * 128 + 255) / 256),  dim3(256), 0, stream>>>(w3, wp3, 3, 128, 256, 128, 128, 8, 2, 768);

    // encoder (fused transpose): trees -> x0 [B][NN][128]
    enc_fused<<<dim3(B), dim3(256), 0, stream>>>(trees, wpe, enc_b, x0);

    // conv1: dense Z_k = x0 @ W1_k^T, gather-sum epilogue -> y1
    conv_gemm<128, 512, false, false>
        <<<dim3(B, 8), dim3(256), 0, stream>>>(x0, indexes, wp1, b1, stats, y1, colmax, partials);
    stats_kernel<<<dim3(1), dim3(256), 0, stream>>>(partials, stats + 0, 8192, (double)((size_t)B * 512 * NN));

    // conv2
    conv_gemm<512, 256, true, false>
        <<<dim3(B, 4), dim3(256), 0, stream>>>(y1, indexes, wp2, b2, stats + 0, y2, colmax, partials);
    stats_kernel<<<dim3(1), dim3(256), 0, stream>>>(partials, stats + 2, 4096, (double)((size_t)B * 256 * NN));

    // conv3: emit per-column raw max (pool fused)
    conv_gemm<256, 128, true, true>
        <<<dim3(B, 2), dim3(256), 0, stream>>>(y2, indexes, wp3, b3, stats + 2, nullptr, colmax, partials);
    stats_kernel<<<dim3(1), dim3(256), 0, stream>>>(partials, stats + 4, 2048, (double)((size_t)B * 128 * NN));

    pool_head_kernel<<<dim3(B), dim3(128), 0, stream>>>(colmax, stats + 4, lat_w, lat_b, cost_w, cost_b, out);
}

// Round 7
// 402.154 us; speedup vs baseline: 2.0654x; 1.1758x over previous
//
#include <hip/hip_runtime.h>
#include <hip/hip_bf16.h>
#include <math.h>

using short8 = __attribute__((ext_vector_type(8))) short;
using f32x16 = __attribute__((ext_vector_type(16))) float;

constexpr int B  = 1024;
constexpr int NN = 128;   // nodes per tree
constexpr int F  = 318;   // raw features

__device__ inline float bf2f(unsigned short u) {
    union { unsigned int i; float f; } x; x.i = ((unsigned int)u) << 16; return x.f;
}
__device__ inline unsigned short f2bf(float f) {
    union { float f; unsigned int i; } x; x.f = f;
    unsigned int r = x.i + 0x7fff + ((x.i >> 16) & 1);
    return (unsigned short)(r >> 16);
}

// ---------- weight prepack into 32x32x16 MFMA B-fragment order ----------
// element t = ((kbg*(COUT/32)+ob)*64+lane)*8+j
// kbg = (k*NCC + cc)*KS + ks ; c = cc*CC + ks*16 + (lane>>5)*8 + j ; o = ob*32 + (lane&31)
__global__ __launch_bounds__(256) void prepack_w32(const float* __restrict__ w,
                                                   unsigned short* __restrict__ wp,
                                                   int kmul, int OREAL, int CREAL,
                                                   int CC, int COUT, int KS, int NCC, int KTOT)
{
    int t = blockIdx.x * 256 + threadIdx.x;
    if (t >= KTOT * COUT) return;
    int j = t & 7;
    int lane = (t >> 3) & 63;
    int rest = t >> 9;
    int obn = COUT / 32;
    int ob = rest % obn;
    int kbg = rest / obn;
    int ks = kbg % KS;
    int t2 = kbg / KS;
    int cc = t2 % NCC;
    int k  = t2 / NCC;
    int c = cc * CC + ks * 16 + (lane >> 5) * 8 + j;
    int o = ob * 32 + (lane & 31);
    float v = 0.f;
    if (c < CREAL && o < OREAL)
        v = (kmul == 3) ? w[((size_t)o * CREAL + c) * 3 + k] : w[(size_t)o * CREAL + c];
    wp[t] = f2bf(v);
}

// ---------- encoder, fused transpose: trees [B][F][NN] f32 -> x0 [B][NN][128] bf16 ----------
__global__ __launch_bounds__(256, 2) void enc_fused(const float* __restrict__ trees,
                                                    const unsigned short* __restrict__ wp,
                                                    const float* __restrict__ bias,
                                                    unsigned short* __restrict__ x0)
{
    constexpr int CC = 64, NCH = 5, KS = 4, NB = 4, OT = 128;
    constexpr int BUFB = NN * CC * 2;       // 16 KB
    __shared__ __align__(16) char gbuf[2 * BUFB];   // dbuf; epilogue reuses 32 KB

    const int b = blockIdx.x;
    const int tid = threadIdx.x;
    const int lane = tid & 63;
    const int wm = tid >> 6;                 // wave = 32 rows
    const int l31 = lane & 31, lh2 = lane >> 5;

    const int cl = tid >> 2;                 // channel-within-chunk 0..63
    const int nq = tid & 3;                  // n-quarter

    float4 vv[8];
    auto load = [&](int ch) {
        const int c = ch * CC + cl;
        const bool ok = (c < F);
        const float* src = trees + ((size_t)b * F + c) * NN + nq * 32;
#pragma unroll
        for (int j = 0; j < 8; ++j)
            vv[j] = ok ? *reinterpret_cast<const float4*>(src + j * 4) : make_float4(0.f, 0.f, 0.f, 0.f);
    };
    const int gsw = cl >> 3, cby = (cl & 7) * 2;
    auto stor = [&](char* wb) {
#pragma unroll
        for (int j = 0; j < 8; ++j) {
            const int n0 = nq * 32 + j * 4;
            const float f4[4] = {vv[j].x, vv[j].y, vv[j].z, vv[j].w};
#pragma unroll
            for (int r = 0; r < 4; ++r) {
                const int n = n0 + r;
                *reinterpret_cast<unsigned short*>(
                    wb + n * (CC * 2) + (((gsw ^ (n & 7)) << 4) + cby)) = f2bf(f4[r]);
            }
        }
    };

    f32x16 acc[NB];
#pragma unroll
    for (int ob = 0; ob < NB; ++ob) acc[ob] = (f32x16)0.f;

    const int nrow = wm * 32 + l31;
    const unsigned abyte = (unsigned)(nrow * (CC * 2));
    const unsigned axor = (unsigned)((nrow & 7) << 4);

    load(0); stor(gbuf);
    __syncthreads();

    int p = 0;
#pragma unroll
    for (int ch = 0; ch < NCH; ++ch) {
        if (ch + 1 < NCH) load(ch + 1);
        const char* base = gbuf + p * BUFB;
#pragma unroll
        for (int ks = 0; ks < KS; ++ks) {
            const int kbg = ch * KS + ks;
            short8 a = *reinterpret_cast<const short8*>(
                base + abyte + (((unsigned)((ks * 2 + lh2) << 4)) ^ axor));
            const unsigned short* wb_ = wp + ((size_t)(kbg * 4) * 64 + lane) * 8;
#pragma unroll
            for (int ob = 0; ob < NB; ++ob) {
                short8 bf_ = *reinterpret_cast<const short8*>(wb_ + ob * 512);
                acc[ob] = __builtin_amdgcn_mfma_f32_32x32x16_bf16(a, bf_, acc[ob], 0, 0, 0);
            }
        }
        if (ch + 1 < NCH) stor(gbuf + (p ^ 1) * BUFB);
        __syncthreads();
        p ^= 1;
    }

    // epilogue
    unsigned short* xs = reinterpret_cast<unsigned short*>(gbuf);
    float bs[NB];
#pragma unroll
    for (int ob = 0; ob < NB; ++ob) {
        int o = ob * 32 + l31;
        bs[ob] = (o < 109) ? bias[o] : 0.f;
    }
#pragma unroll
    for (int ob = 0; ob < NB; ++ob)
#pragma unroll
        for (int r = 0; r < 16; ++r) {
            float val = acc[ob][r] + bs[ob];
            int row = wm * 32 + (r & 3) + 8 * (r >> 2) + 4 * lh2;
            xs[row * OT + ob * 32 + l31] = f2bf(val);
        }
    __syncthreads();
#pragma unroll
    for (int i = 0; i < 8; ++i) {
        int e = i * 256 + tid;
        int n = e >> 4, g = e & 15;
        *reinterpret_cast<uint4*>(x0 + ((size_t)b * NN + n) * 128 + g * 8)
            = *reinterpret_cast<const uint4*>(xs + n * OT + g * 8);
    }
}

// ---------- tree conv: DENSE GEMM (3 weight planes share staged A) + output-side gather ----------
// Z_k = T(x) @ W_k^T computed dense; y[n][o] = bias[o] + sum_k Z_k[idx[3n+k]][o]
// T(v) = NORM ? max(v*inv - mu*inv, 0) : v  (once, at stage time)
// COLMAX: emit per-column max over n (raw, biased) instead of y (for final layer + pooling).
// Grid: flat B*OTN blocks, XCD-swizzled so all OTN o-tiles of one b land adjacently on ONE XCD
// (round-robin dispatch): xcd=f&7, s=f>>3, b=xcd+8*(s/OTN), oy=s%OTN  ->  x[b] is L2-resident.
template <int CIN, int COUT, int OTN, bool NORM, bool COLMAX>
__global__ __launch_bounds__(256, 2) void conv_gemm(const unsigned short* __restrict__ xin, // [B][NN][CIN]
                                                    const int* __restrict__ idx,            // [B][3*NN]
                                                    const unsigned short* __restrict__ wp,
                                                    const float* __restrict__ bias,
                                                    const float* __restrict__ stats,
                                                    unsigned short* __restrict__ yout,      // [B][NN][COUT]
                                                    float* __restrict__ colmax,             // [B][COUT]
                                                    float* __restrict__ partials)
{
    constexpr int CC    = 128;
    constexpr int NCC   = CIN / CC;
    constexpr int KS    = 8;                  // k-steps per chunk (CC/16)
    constexpr int ITERS = 8;                  // staging granules per thread
    constexpr int BUFB  = NN * CC * 2;        // 32 KB
    constexpr int DB    = (NCC > 1) ? 2 * BUFB : BUFB;
    constexpr int ZB    = 3 * NN * 32 * 4;    // 48 KB f32 Z tiles
    constexpr int SMEM  = (DB > ZB) ? DB : ZB;

    __shared__ __align__(16) char gbuf[SMEM];
    __shared__ float rbuf[8];
    __shared__ float cmax[4][2][16];

    // XCD-grouping decode
    const int f  = blockIdx.x;
    const int s  = f >> 3;
    const int b  = (f & 7) + 8 * (s / OTN);
    const int oy = s % OTN;                   // o-tile base = oy*64

    const int tid = threadIdx.x;
    const int lane = tid & 63;
    const int wv = tid >> 6;
    const int wm = wv >> 1, wn = wv & 1;
    const int l31 = lane & 31, lh2 = lane >> 5;

    float inv = 1.f, nmi = 0.f;
    if (NORM) { float mu = stats[0]; inv = stats[1]; nmi = -mu * inv; }

    const unsigned short* xb = xin + (size_t)b * NN * CIN;

    // dense staging descriptors (coalesced global, swizzled LDS)
    const int g = tid & 15;
    unsigned ngoff[ITERS], lby[ITERS];
#pragma unroll
    for (int i = 0; i < ITERS; ++i) {
        int n = (i * 256 + tid) >> 4;
        ngoff[i] = (unsigned)(n * CIN + g * 8);
        lby[i]   = (unsigned)(n * 256 + ((g ^ (n & 15)) << 4));
    }

    // gather rows for the epilogue (per-thread output row)
    const int en = tid >> 1, eh = tid & 1;
    int sk[3];
#pragma unroll
    for (int k = 0; k < 3; ++k) sk[k] = idx[b * 3 * NN + 3 * en + k];

    f32x16 acc[2][3];                          // [nfrag][kplane]
#pragma unroll
    for (int nf = 0; nf < 2; ++nf)
#pragma unroll
        for (int k = 0; k < 3; ++k) acc[nf][k] = (f32x16)0.f;

    uint4 v[ITERS];
    auto load = [&](int cc) {
#pragma unroll
        for (int i = 0; i < ITERS; ++i)
            v[i] = *reinterpret_cast<const uint4*>(xb + cc * CC + ngoff[i]);
    };
    auto stor = [&](char* wb) {
#pragma unroll
        for (int i = 0; i < ITERS; ++i) {
            uint4 t = v[i];
            if (NORM) {
                unsigned int* pw = reinterpret_cast<unsigned int*>(&t);
#pragma unroll
                for (int q = 0; q < 4; ++q) {
                    unsigned int u = pw[q];
                    float f0 = __uint_as_float(u << 16);
                    float f1 = __uint_as_float(u & 0xffff0000u);
                    f0 = fmaxf(fmaf(f0, inv, nmi), 0.f);
                    f1 = fmaxf(fmaf(f1, inv, nmi), 0.f);
                    unsigned int r;
                    asm("v_cvt_pk_bf16_f32 %0, %1, %2" : "=v"(r) : "v"(f0), "v"(f1));
                    pw[q] = r;
                }
            }
            *reinterpret_cast<uint4*>(wb + lby[i]) = t;
        }
    };

    // A-read bases: rows wave-deterministic (dense!)
    const int n0 = wm * 64 + l31;
    const int n1 = n0 + 32;
    const unsigned a0b = (unsigned)(n0 * 256), a0x = (unsigned)((n0 & 15) << 4);
    const unsigned a1b = (unsigned)(n1 * 256), a1x = (unsigned)((n1 & 15) << 4);
    const int obg = oy * 2 + wn;

    load(0); stor(gbuf);
    __syncthreads();

    int p = 0;
#pragma unroll
    for (int cc = 0; cc < NCC; ++cc) {
        if (cc + 1 < NCC) load(cc + 1);
        const char* base = gbuf + p * BUFB;
#pragma unroll
        for (int ks = 0; ks < KS; ++ks) {
            const unsigned so = (unsigned)((ks * 2 + lh2) << 4);
            short8 a0 = *reinterpret_cast<const short8*>(base + a0b + (so ^ a0x));
            short8 a1 = *reinterpret_cast<const short8*>(base + a1b + (so ^ a1x));
#pragma unroll
            for (int k = 0; k < 3; ++k) {
                const size_t kbg = (size_t)((k * NCC + cc) * KS + ks);
                short8 bf_ = *reinterpret_cast<const short8*>(
                    wp + ((kbg * (COUT / 32) + obg) * 64 + lane) * 8);
                acc[0][k] = __builtin_amdgcn_mfma_f32_32x32x16_bf16(a0, bf_, acc[0][k], 0, 0, 0);
                acc[1][k] = __builtin_amdgcn_mfma_f32_32x32x16_bf16(a1, bf_, acc[1][k], 0, 0, 0);
            }
        }
        if (cc + 1 < NCC) stor(gbuf + (p ^ 1) * BUFB);
        __syncthreads();
        p ^= 1;
    }

    // ---------------- epilogue: Z -> LDS (f32, quad-swizzled), output-side gather ----------------
    float* Z = reinterpret_cast<float*>(gbuf);
    float tsum = 0.f, tss = 0.f;
#pragma unroll
    for (int oh = 0; oh < 2; ++oh) {
        if (oh) __syncthreads();
        if (wn == oh) {
#pragma unroll
            for (int k = 0; k < 3; ++k)
#pragma unroll
                for (int nf = 0; nf < 2; ++nf)
#pragma unroll
                    for (int r = 0; r < 16; ++r) {
                        int row = wm * 64 + nf * 32 + (r & 3) + 8 * (r >> 2) + 4 * lh2;
                        Z[(k * NN + row) * 32 + (l31 ^ ((row & 7) << 2))] = acc[nf][k][r];
                    }
        }
        __syncthreads();

        // per-thread: 16 outputs, row en, cols eh*16..+15 of this o-half
        float val[16];
        {
            const float* bp = bias + oy * 64 + oh * 32 + eh * 16;
#pragma unroll
            for (int j = 0; j < 16; ++j) val[j] = bp[j];
        }
#pragma unroll
        for (int k = 0; k < 3; ++k) {
            const float* zr = Z + (k * NN + sk[k]) * 32;
            const int sw = sk[k] & 7;
#pragma unroll
            for (int q4 = 0; q4 < 4; ++q4) {
                const int q = eh * 4 + q4;
                float4 z = *reinterpret_cast<const float4*>(zr + ((q ^ sw) << 2));
                val[q4 * 4 + 0] += z.x;
                val[q4 * 4 + 1] += z.y;
                val[q4 * 4 + 2] += z.z;
                val[q4 * 4 + 3] += z.w;
            }
        }
#pragma unroll
        for (int j = 0; j < 16; ++j) { tsum += val[j]; tss += val[j] * val[j]; }

        if (COLMAX) {
            // butterfly max across the 32 n-rows in this wave (keep col-half parity = lane bit0)
#pragma unroll
            for (int m = 2; m <= 32; m <<= 1)
#pragma unroll
                for (int j = 0; j < 16; ++j) val[j] = fmaxf(val[j], __shfl_xor(val[j], m));
            if ((lane >> 1) == 0) {
#pragma unroll
                for (int j = 0; j < 16; ++j) cmax[wv][lane & 1][j] = val[j];
            }
            __syncthreads();
            if (tid < 32) {
                float m = fmaxf(fmaxf(cmax[0][tid >> 4][tid & 15], cmax[1][tid >> 4][tid & 15]),
                                fmaxf(cmax[2][tid >> 4][tid & 15], cmax[3][tid >> 4][tid & 15]));
                colmax[b * COUT + oy * 64 + oh * 32 + tid] = m;
            }
        } else {
            unsigned int pk[8];
#pragma unroll
            for (int j = 0; j < 8; ++j)
                pk[j] = (unsigned int)f2bf(val[2 * j]) | ((unsigned int)f2bf(val[2 * j + 1]) << 16);
            unsigned short* dst = yout + ((size_t)b * NN + en) * COUT + oy * 64 + oh * 32 + eh * 16;
            reinterpret_cast<uint4*>(dst)[0] = make_uint4(pk[0], pk[1], pk[2], pk[3]);
            reinterpret_cast<uint4*>(dst)[1] = make_uint4(pk[4], pk[5], pk[6], pk[7]);
        }
    }

    // block stats reduction
#pragma unroll
    for (int ss = 32; ss; ss >>= 1) { tsum += __shfl_down(tsum, ss); tss += __shfl_down(tss, ss); }
    if (lane == 0) { rbuf[wv * 2] = tsum; rbuf[wv * 2 + 1] = tss; }
    __syncthreads();
    if (tid == 0) {
        float sm = rbuf[0] + rbuf[2] + rbuf[4] + rbuf[6];
        float q = rbuf[1] + rbuf[3] + rbuf[5] + rbuf[7];
        int gid = oy * B + b;
        partials[2 * gid] = sm;
        partials[2 * gid + 1] = q;
    }
}

// ---------- finalize global layernorm stats ----------
__global__ __launch_bounds__(256) void stats_kernel(const float* __restrict__ partials,
                                                    float* __restrict__ stats,
                                                    int npart, double ntot)
{
    __shared__ double sd[256], sd2[256];
    double s = 0.0, s2 = 0.0;
    for (int i = threadIdx.x; i < npart; i += 256) { s += (double)partials[2 * i]; s2 += (double)partials[2 * i + 1]; }
    sd[threadIdx.x] = s; sd2[threadIdx.x] = s2;
    __syncthreads();
    for (int k = 128; k > 0; k >>= 1) {
        if (threadIdx.x < k) { sd[threadIdx.x] += sd[threadIdx.x + k]; sd2[threadIdx.x] += sd2[threadIdx.x + k]; }
        __syncthreads();
    }
    if (threadIdx.x == 0) {
        double mu = sd[0] / ntot;
        double var = (sd2[0] - sd[0] * sd[0] / ntot) / (ntot - 1.0);
        double sdv = sqrt(var > 0.0 ? var : 0.0);
        stats[0] = (float)mu;
        stats[1] = (float)(1.0 / (sdv + 1e-5));
    }
}

// ---------- heads from per-column max (raw) ----------
__global__ __launch_bounds__(128) void pool_head_kernel(const float* __restrict__ colmax,  // [B][128]
                                                        const float* __restrict__ stats,
                                                        const float* __restrict__ latw,
                                                        const float* __restrict__ latb,
                                                        const float* __restrict__ costw,
                                                        const float* __restrict__ costb,
                                                        float* __restrict__ out)
{
    const int b = blockIdx.x, t = threadIdx.x;
    const float mu = stats[0], inv = stats[1];
    const float pooled = fmaxf((colmax[b * 128 + t] - mu) * inv, 0.f);
    __shared__ float pl[128];
    pl[t] = pooled;
    __syncthreads();
    const float* w = (t < 64) ? latw : costw;
    const int l = t & 63;
    float v = pl[l] * w[l] + pl[l + 64] * w[l + 64];
#pragma unroll
    for (int s = 32; s > 0; s >>= 1) v += __shfl_down(v, s);
    if (l == 0) {
        const float bb = (t < 64) ? latb[0] : costb[0];
        out[(t < 64 ? 0 : B) + b] = 1.f / (1.f + expf(-(v + bb)));
    }
}

// ---------- launch ----------
extern "C" void kernel_launch(void* const* d_in, const int* in_sizes, int n_in,
                              void* d_out, int out_size, void* d_ws, size_t ws_size,
                              hipStream_t stream)
{
    (void)in_sizes; (void)n_in; (void)out_size; (void)ws_size;
    const float* trees   = (const float*)d_in[0];
    const int*   indexes = (const int*)  d_in[1];
    const float* enc_w   = (const float*)d_in[2];
    const float* enc_b   = (const float*)d_in[3];
    const float* w1 = (const float*)d_in[4];
    const float* b1 = (const float*)d_in[5];
    const float* w2 = (const float*)d_in[6];
    const float* b2 = (const float*)d_in[7];
    const float* w3 = (const float*)d_in[8];
    const float* b3 = (const float*)d_in[9];
    const float* lat_w  = (const float*)d_in[10];
    const float* lat_b  = (const float*)d_in[11];
    const float* cost_w = (const float*)d_in[12];
    const float* cost_b = (const float*)d_in[13];
    float* out = (float*)d_out;

    char* ws = (char*)d_ws;
    size_t off = 0;
    auto alloc = [&](size_t bytes) -> char* {
        char* p = ws + off;
        off += (bytes + 255) & ~(size_t)255;
        return p;
    };
    unsigned short* wpe = (unsigned short*)alloc((size_t)320 * 128 * 2);
    unsigned short* wp1 = (unsigned short*)alloc((size_t)384 * 512 * 2);
    unsigned short* wp2 = (unsigned short*)alloc((size_t)1536 * 256 * 2);
    unsigned short* wp3 = (unsigned short*)alloc((size_t)768 * 128 * 2);
    unsigned short* x0  = (unsigned short*)alloc((size_t)B * NN * 128 * 2);
    unsigned short* y1  = (unsigned short*)alloc((size_t)B * NN * 512 * 2);
    unsigned short* y2  = (unsigned short*)alloc((size_t)B * NN * 256 * 2);
    float* colmax   = (float*)alloc((size_t)B * 128 * 4);
    float* partials = (float*)alloc((size_t)8192 * 2 * 4);
    float* stats    = (float*)alloc(8 * 4);

    prepack_w32<<<dim3((320 * 128 + 255) / 256),  dim3(256), 0, stream>>>(enc_w, wpe, 1, 109, 318, 64, 128, 4, 5, 320);
    prepack_w32<<<dim3((384 * 512 + 255) / 256),  dim3(256), 0, stream>>>(w1, wp1, 3, 512, 109, 128, 512, 8, 1, 384);
    prepack_w32<<<dim3((1536 * 256 + 255) / 256), dim3(256), 0, stream>>>(w2, wp2, 3, 256, 512, 128, 256, 8, 4, 1536);
    prepack_w32<<<dim3((768 * 128 + 255) / 256),  dim3(256), 0, stream>>>(w3, wp3, 3, 128, 256, 128, 128, 8, 2, 768);

    // encoder (fused transpose): trees -> x0 [B][NN][128]
    enc_fused<<<dim3(B), dim3(256), 0, stream>>>(trees, wpe, enc_b, x0);

    // conv1: dense Z_k = x0 @ W1_k^T, gather-sum epilogue -> y1 (8 o-tiles, XCD-grouped per b)
    conv_gemm<128, 512, 8, false, false>
        <<<dim3(B * 8), dim3(256), 0, stream>>>(x0, indexes, wp1, b1, stats, y1, colmax, partials);
    stats_kernel<<<dim3(1), dim3(256), 0, stream>>>(partials, stats + 0, 8192, (double)((size_t)B * 512 * NN));

    // conv2
    conv_gemm<512, 256, 4, true, false>
        <<<dim3(B * 4), dim3(256), 0, stream>>>(y1, indexes, wp2, b2, stats + 0, y2, colmax, partials);
    stats_kernel<<<dim3(1), dim3(256), 0, stream>>>(partials, stats + 2, 4096, (double)((size_t)B * 256 * NN));

    // conv3: emit per-column raw max (pool fused)
    conv_gemm<256, 128, 2, true, true>
        <<<dim3(B * 2), dim3(256), 0, stream>>>(y2, indexes, wp3, b3, stats + 2, nullptr, colmax, partials);
    stats_kernel<<<dim3(1), dim3(256), 0, stream>>>(partials, stats + 4, 2048, (double)((size_t)B * 128 * NN));

    pool_head_kernel<<<dim3(B), dim3(128), 0, stream>>>(colmax, stats + 4, lat_w, lat_b, cost_w, cost_b, out);
}